// Round 6
// baseline (168.403 us; speedup 1.0000x reference)
//
#include <hip/hip_runtime.h>

#define N_TOK 131072
#define TILE 32              // tokens per block (one tile per block)
#define NT_MAX 4112          // N_TOK/TILE + 16 tasks worth of padding tiles

typedef __attribute__((ext_vector_type(8))) short s8v;
typedef __attribute__((ext_vector_type(4))) float f4v;
typedef unsigned short ushort_t;

__device__ __forceinline__ unsigned short f2bf(float x) {
    union { float f; unsigned u; } v; v.f = x;
    unsigned r = v.u + 0x7fffu + ((v.u >> 16) & 1u);   // RNE (prep only)
    return (unsigned short)(r >> 16);
}

// round-half-up pack of two f32 -> packed bf16x2 via v_perm_b32 (3 VALU ops)
__device__ __forceinline__ unsigned pk2(float a, float b) {
    union { float f; unsigned u; } x, y; x.f = a; y.f = b;
    return __byte_perm(x.u + 0x8000u, y.u + 0x8000u, 0x7632);
}

// tanh = 1 - 2/(e^2x+1); e^2x = exp2(x * 2*log2(e)): mul, exp2, add, rcp, fma
__device__ __forceinline__ float tanh_fast(float x) {
    float e = __builtin_amdgcn_exp2f(x * 2.8853900817779268f);
    float r = __builtin_amdgcn_rcpf(e + 1.0f);
    return __builtin_fmaf(-2.0f, r, 1.0f);
}

// ------------------------------------------------- fused prep + hist
// blocks [0,224): repack weights to bf16 MFMA fragments (one 16B write/thread).
// Fragment r = (ftile*(K>>5)+kt)*64 + lane; elem j holds W[k][n] with
// n = ftile*16 + (lane&15), k = kt*32 + (lane>>4)*8 + j.  (A operand of
// Y^T = W^T X^T.)   blocks [224,288): 16-bin histogram of task[].
__global__ void prep_hist_kernel(const float* __restrict__ W0, const float* __restrict__ W1,
                                 const float* __restrict__ W2,
                                 ushort_t* __restrict__ W0p, ushort_t* __restrict__ W1p,
                                 ushort_t* __restrict__ W2p,
                                 const int* __restrict__ task, int* __restrict__ blockCounts) {
    if (blockIdx.x < 224) {
        int f = blockIdx.x * 256 + threadIdx.x;   // 57344 total fragments
        const float* src; ushort_t* dst; int K, N;
        if (f < 16384)      { src = W0; dst = W0p; K = 128; N = 256; }
        else if (f < 49152) { src = W1; dst = W1p; K = 256; N = 256; f -= 16384; }
        else                { src = W2; dst = W2p; K = 256; N = 64;  f -= 49152; }
        int fpc = (N >> 4) * (K >> 5) * 64;       // fragments per copy
        int c = f / fpc, r = f % fpc;
        int lane = r & 63;
        int kt = (r >> 6) % (K >> 5);
        int ftile = (r >> 6) / (K >> 5);
        int n = ftile * 16 + (lane & 15);
        int kbase = kt * 32 + (lane >> 4) * 8;
        const float* s = src + (size_t)c * K * N + (size_t)kbase * N + n;
        s8v pk;
#pragma unroll
        for (int j = 0; j < 8; j++) pk[j] = (short)f2bf(s[(size_t)j * N]);
        *reinterpret_cast<s8v*>(dst + ((size_t)(c * fpc + r) << 3)) = pk;
    } else {
        __shared__ int cnt[16];
        int t = threadIdx.x;
        int hb = blockIdx.x - 224;
        if (t < 16) cnt[t] = 0;
        __syncthreads();
        int base = hb * 2048 + t;
#pragma unroll
        for (int i = 0; i < 8; i++) atomicAdd(&cnt[task[base + i * 256]], 1);
        __syncthreads();
        if (t < 16) blockCounts[hb * 16 + t] = cnt[t];
    }
}

// ------------------------------------------------- fused scan + scatter
__global__ void sort_kernel(const int* __restrict__ task, const int* __restrict__ blockCounts,
                            int* __restrict__ tileTask, int* __restrict__ nT,
                            int* __restrict__ perm) {
    __shared__ int cntLds[1024];
    __shared__ int total[16], pref[16], rank[16];
    __shared__ int tokBase[16], tbase[17];
    int t = threadIdx.x, b = blockIdx.x;
    for (int i = t; i < 1024; i += 256) cntLds[i] = blockCounts[i];
    if (t < 16) rank[t] = 0;
    __syncthreads();
    if (t < 16) {
        int tot = 0, pf = 0;
#pragma unroll
        for (int bb = 0; bb < 64; bb++) {
            int v = cntLds[bb * 16 + t];
            tot += v;
            if (bb < b) pf += v;
        }
        total[t] = tot; pref[t] = pf;
    }
    __syncthreads();
    if (t == 0) {
        int tok = 0, tile = 0;
        for (int k = 0; k < 16; k++) {
            tokBase[k] = tok;
            tbase[k] = tile;
            int ntk = (total[k] + TILE - 1) / TILE;
            tok += ntk * TILE;
            tile += ntk;
        }
        tbase[16] = tile;
        if (b == 0) nT[0] = tile;
    }
    __syncthreads();
    if (b == 0) {
        for (int i = t; i < NT_MAX; i += 256) {
            int tk = 0;
            if (i < tbase[16]) {
#pragma unroll
                for (int k = 0; k < 16; k++) if (i >= tbase[k]) tk = k;
            }
            tileTask[i] = tk;
        }
        // fill padding slots with -1 (don't rely on ws poison being >= N_TOK)
        for (int i = t; i < 16 * TILE; i += 256) {
            int k = i >> 5, off = i & (TILE - 1);
            int idx = total[k] + off;
            int lim = ((total[k] + TILE - 1) / TILE) * TILE;
            if (idx < lim) perm[tokBase[k] + idx] = -1;
        }
    }
    int tk[8], my[8];
#pragma unroll
    for (int i = 0; i < 8; i++) {
        int idx = b * 2048 + i * 256 + t;
        tk[i] = task[idx];
        my[i] = atomicAdd(&rank[tk[i]], 1);
    }
#pragma unroll
    for (int i = 0; i < 8; i++) {
        int idx = b * 2048 + i * 256 + t;
        perm[tokBase[tk[i]] + pref[tk[i]] + my[i]] = idx;
    }
}

// ------------------------------------------------- fused MLP, 4-wave blocks
// One 32-token tile per block, 4 waves, feature dim split 4-ways (was 8):
// each activation fragment is read by 4 waves instead of 8 -> LDS read volume
// 8 -> 5 KB/token. 32KB LDS + ~100 VGPR -> 4 independent blocks/CU at
// naturally different phases: ds_read / MFMA / tanh / weight-load latency
// overlap ACROSS blocks instead of serializing inside one barrier-locked
// block (the round-0..4 ~64us plateau). Weights streamed from L2 (measured
// cost of the stream: ~4-8us total; residency attempts were chasing noise).
__launch_bounds__(256, 4)
__global__ void mlp_kernel(const float* __restrict__ x_in,
                           const int* __restrict__ cmap,
                           const float* __restrict__ b0,
                           const float* __restrict__ b1,
                           const float* __restrict__ b2,
                           const ushort_t* __restrict__ W0p,
                           const ushort_t* __restrict__ W1p,
                           const ushort_t* __restrict__ W2p,
                           const int* __restrict__ tileTask,
                           const int* __restrict__ nTp,
                           const int* __restrict__ perm,
                           float* __restrict__ out) {
    __shared__ __align__(16) ushort_t H1[8192];    // 2 tt * 8 kt * 64 * 8 = 16 KB
    __shared__ __align__(16) ushort_t XH2[8192];   // X: frags [0,8) (8 KB); H2: frags [0,16)

    int b = blockIdx.x;
    if (b >= nTp[0]) return;
    int t = threadIdx.x;
    int task = tileTask[b];
    int c0 = cmap[task], c1 = cmap[16 + task], c2 = cmap[32 + task];

    int w = t >> 6;                 // wave 0..3
    int lane = t & 63;
    int l15 = lane & 15, lq = lane >> 4;

    // ---- stage X: gather + cvt straight into B-fragment order (two b128/thread)
    {
        int r = t >> 3, q = t & 7;             // token r (0..31), covers k = q*16..q*16+15
        int tok = perm[b * TILE + r];
        float4 v0 = make_float4(0.f, 0.f, 0.f, 0.f), v1 = v0, v2 = v0, v3 = v0;
        if ((unsigned)tok < (unsigned)N_TOK) {
            const float4* src = reinterpret_cast<const float4*>(x_in) + (size_t)tok * 32 + q * 4;
            v0 = src[0]; v1 = src[1]; v2 = src[2]; v3 = src[3];
        }
        // frag coords: kt = q>>1, fragid = (r>>4)*4 + kt
        // half h (elems h*8..h*8+7): lane' = (r&15) + 16*((q&1)*2 + h)
        int fragid = (r >> 4) * 4 + (q >> 1);
        int lp0 = (r & 15) + 16 * ((q & 1) * 2);
        uint4 pk0, pk1;
        pk0.x = pk2(v0.x, v0.y); pk0.y = pk2(v0.z, v0.w);
        pk0.z = pk2(v1.x, v1.y); pk0.w = pk2(v1.z, v1.w);
        pk1.x = pk2(v2.x, v2.y); pk1.y = pk2(v2.z, v2.w);
        pk1.z = pk2(v3.x, v3.y); pk1.w = pk2(v3.z, v3.w);
        *reinterpret_cast<uint4*>(&XH2[(fragid * 64 + lp0) << 3]) = pk0;
        *reinterpret_cast<uint4*>(&XH2[(fragid * 64 + lp0 + 16) << 3]) = pk1;
    }
    __syncthreads();

    // ---- Layer 0: H1^T = W0^T X^T. Wave w: feature tiles {4w..4w+3} x 2 token tiles.
    {
        f4v acc[4][2];
#pragma unroll
        for (int mi = 0; mi < 4; mi++) {
            f4v bv = *reinterpret_cast<const f4v*>(b0 + c0 * 256 + (4 * w + mi) * 16 + lq * 4);
            acc[mi][0] = bv; acc[mi][1] = bv;
        }
        const ushort_t* Wc = W0p + (size_t)c0 * 32768;
#pragma unroll
        for (int kt = 0; kt < 4; kt++) {
            s8v wa[4];
#pragma unroll
            for (int mi = 0; mi < 4; mi++)
                wa[mi] = *reinterpret_cast<const s8v*>(Wc + ((((4 * w + mi) * 4 + kt) * 64 + lane) << 3));
            s8v xb[2];
#pragma unroll
            for (int nt = 0; nt < 2; nt++)
                xb[nt] = *reinterpret_cast<const s8v*>(&XH2[((nt * 4 + kt) * 64 + lane) << 3]);
            __builtin_amdgcn_s_setprio(1);
#pragma unroll
            for (int mi = 0; mi < 4; mi++)
#pragma unroll
                for (int nt = 0; nt < 2; nt++)
                    acc[mi][nt] = __builtin_amdgcn_mfma_f32_16x16x32_bf16(wa[mi], xb[nt], acc[mi][nt], 0, 0, 0);
            __builtin_amdgcn_s_setprio(0);
        }
#pragma unroll
        for (int mi = 0; mi < 4; mi++) {
            int ft = 4 * w + mi;
            int kt_h = ft >> 1;
            int lanep = l15 + 16 * ((ft & 1) * 2 + (lq >> 1));
            int j0 = (lq & 1) * 4;
#pragma unroll
            for (int nt = 0; nt < 2; nt++) {
                float t0 = tanh_fast(acc[mi][nt][0]);
                float t1 = tanh_fast(acc[mi][nt][1]);
                float t2 = tanh_fast(acc[mi][nt][2]);
                float t3 = tanh_fast(acc[mi][nt][3]);
                uint2 pk; pk.x = pk2(t0, t1); pk.y = pk2(t2, t3);
                *reinterpret_cast<uint2*>(&H1[(((nt * 8 + kt_h) * 64 + lanep) << 3) + j0]) = pk;
            }
        }
    }
    __syncthreads();

    // ---- Layer 1: H2^T = W1^T H1^T. (H2 overlays X region.)
    {
        f4v acc[4][2];
#pragma unroll
        for (int mi = 0; mi < 4; mi++) {
            f4v bv = *reinterpret_cast<const f4v*>(b1 + c1 * 256 + (4 * w + mi) * 16 + lq * 4);
            acc[mi][0] = bv; acc[mi][1] = bv;
        }
        const ushort_t* Wc = W1p + (size_t)c1 * 65536;
#pragma unroll
        for (int kt = 0; kt < 8; kt++) {
            s8v wa[4];
#pragma unroll
            for (int mi = 0; mi < 4; mi++)
                wa[mi] = *reinterpret_cast<const s8v*>(Wc + ((((4 * w + mi) * 8 + kt) * 64 + lane) << 3));
            s8v xb[2];
#pragma unroll
            for (int nt = 0; nt < 2; nt++)
                xb[nt] = *reinterpret_cast<const s8v*>(&H1[((nt * 8 + kt) * 64 + lane) << 3]);
            __builtin_amdgcn_s_setprio(1);
#pragma unroll
            for (int mi = 0; mi < 4; mi++)
#pragma unroll
                for (int nt = 0; nt < 2; nt++)
                    acc[mi][nt] = __builtin_amdgcn_mfma_f32_16x16x32_bf16(wa[mi], xb[nt], acc[mi][nt], 0, 0, 0);
            __builtin_amdgcn_s_setprio(0);
        }
#pragma unroll
        for (int mi = 0; mi < 4; mi++) {
            int ft = 4 * w + mi;
            int kt_h = ft >> 1;
            int lanep = l15 + 16 * ((ft & 1) * 2 + (lq >> 1));
            int j0 = (lq & 1) * 4;
#pragma unroll
            for (int nt = 0; nt < 2; nt++) {
                float t0 = tanh_fast(acc[mi][nt][0]);
                float t1 = tanh_fast(acc[mi][nt][1]);
                float t2 = tanh_fast(acc[mi][nt][2]);
                float t3 = tanh_fast(acc[mi][nt][3]);
                uint2 pk; pk.x = pk2(t0, t1); pk.y = pk2(t2, t3);
                *reinterpret_cast<uint2*>(&XH2[(((nt * 8 + kt_h) * 64 + lanep) << 3) + j0]) = pk;
            }
        }
    }
    __syncthreads();

    // ---- Layer 2: O^T = W2^T H2^T. 4 mt tiles / 4 waves = 1 mt x 2 nt per wave.
    {
        int tok0 = perm[b * TILE + l15];            // nt=0 tokens, issued early
        int tok1 = perm[b * TILE + 16 + l15];       // nt=1 tokens
        f4v bv = *reinterpret_cast<const f4v*>(b2 + c2 * 64 + w * 16 + lq * 4);
        f4v acc[2];
        acc[0] = bv; acc[1] = bv;
        const ushort_t* Wc = W2p + (size_t)c2 * 16384;
#pragma unroll
        for (int kt = 0; kt < 8; kt++) {
            s8v wa = *reinterpret_cast<const s8v*>(Wc + (((w * 8 + kt) * 64 + lane) << 3));
            s8v xb0 = *reinterpret_cast<const s8v*>(&XH2[((0 * 8 + kt) * 64 + lane) << 3]);
            s8v xb1 = *reinterpret_cast<const s8v*>(&XH2[((1 * 8 + kt) * 64 + lane) << 3]);
            __builtin_amdgcn_s_setprio(1);
            acc[0] = __builtin_amdgcn_mfma_f32_16x16x32_bf16(wa, xb0, acc[0], 0, 0, 0);
            acc[1] = __builtin_amdgcn_mfma_f32_16x16x32_bf16(wa, xb1, acc[1], 0, 0, 0);
            __builtin_amdgcn_s_setprio(0);
        }
#pragma unroll
        for (int e = 0; e < 2; e++) {
            int tok = e ? tok1 : tok0;
            if ((unsigned)tok < (unsigned)N_TOK) {
                float4 o;
                o.x = acc[e][0]; o.y = acc[e][1]; o.z = acc[e][2]; o.w = acc[e][3];
                *reinterpret_cast<float4*>(out + (size_t)tok * 64 + w * 16 + lq * 4) = o;
            }
        }
    }
}

// ---------------------------------------------------------------- launch
extern "C" void kernel_launch(void* const* d_in, const int* in_sizes, int n_in,
                              void* d_out, int out_size, void* d_ws, size_t ws_size,
                              hipStream_t stream) {
    const float* inputs = (const float*)d_in[0];
    const int*   task   = (const int*)d_in[1];
    const int*   cmap   = (const int*)d_in[2];
    const float* W0     = (const float*)d_in[3];
    const float* b0     = (const float*)d_in[4];
    const float* W1     = (const float*)d_in[5];
    const float* b1     = (const float*)d_in[6];
    const float* W2     = (const float*)d_in[7];
    const float* b2     = (const float*)d_in[8];
    float* out = (float*)d_out;

    char* ws = (char*)d_ws;
    int* blockCounts = (int*)(ws + 0);            // 64*16*4 = 4096 B
    int* nT          = (int*)(ws + 4096);         // 4 B (pad to 64)
    int* tileTask    = (int*)(ws + 4160);         // 4112*4 = 16448 B -> ends 20608
    int* perm        = (int*)(ws + 20608);        // 4112*32*4 = 526336 B -> ends 546944
    ushort_t* W0p    = (ushort_t*)(ws + 546944);  // 262144 B
    ushort_t* W1p    = (ushort_t*)(ws + 809088);  // 524288 B
    ushort_t* W2p    = (ushort_t*)(ws + 1333376); // 131072 B -> total ~1.40 MB

    prep_hist_kernel<<<288, 256, 0, stream>>>(W0, W1, W2, W0p, W1p, W2p, task, blockCounts);
    sort_kernel<<<64, 256, 0, stream>>>(task, blockCounts, tileTask, nT, perm);
    mlp_kernel<<<NT_MAX, 256, 0, stream>>>(inputs, cmap, b0, b1, b2,
                                           W0p, W1p, W2p, tileTask, nT, perm, out);
}